// Round 13
// baseline (134.380 us; speedup 1.0000x reference)
//
#include <hip/hip_runtime.h>
#include <hip/hip_bf16.h>

constexpr int KD = 1024;
constexpr int ND = 512;
constexpr int NT = 32;           // K tiles of 32
constexpr float EPSV = 1e-5f;

using f32x4  = __attribute__((ext_vector_type(4))) float;
using bf16x8 = __attribute__((ext_vector_type(8))) short;
using u16x8  = __attribute__((ext_vector_type(8))) unsigned short;

__device__ __forceinline__ unsigned short f2bf(float f) {
  unsigned int u = __builtin_bit_cast(unsigned int, f);
  return (unsigned short)((u + 0x7fffu + ((u >> 16) & 1u)) >> 16);  // RNE
}

__device__ __forceinline__ u16x8 pack8(float4 a, float4 b) {
  u16x8 v;
  v[0] = f2bf(a.x); v[1] = f2bf(a.y); v[2] = f2bf(a.z); v[3] = f2bf(a.w);
  v[4] = f2bf(b.x); v[5] = f2bf(b.y); v[6] = f2bf(b.z); v[7] = f2bf(b.w);
  return v;
}

__device__ __forceinline__ unsigned short cvt1(float f) {
  __hip_bfloat16 h = __float2bfloat16(f);          // compiler-lowered RNE cvt
  return __builtin_bit_cast(unsigned short, h);
}

#define SCHEDB()  __builtin_amdgcn_sched_barrier(0)

// Barrier WITHOUT vmcnt drain (m201/m218 idiom; R12 verified +3 us, pass):
// lgkmcnt(0) covers every cross-wave LDS hazard; in-flight GLOBAL loads
// target only the issuing wave's registers (gated by compiler vmcnt).
#define BARRIER() do { \
    asm volatile("s_waitcnt lgkmcnt(0)" ::: "memory"); \
    __builtin_amdgcn_sched_barrier(0); \
    __builtin_amdgcn_s_barrier(); \
    __builtin_amdgcn_sched_barrier(0); } while (0)

// wconvert: w [512][1024] f32 -> wb in MFMA-fragment-major bf16 layout.
// unit uid = (s*32 + nf)*64 + lane   (16 B each; s = k-slice 0..31, nf = n-frag)
// holds w[n = nf*16 + (lane&15)][k = s*32 + (lane>>4)*8 + e], e = 0..7.
__global__ void wconvert_kernel(const float* __restrict__ w,
                                unsigned short* __restrict__ wb) {
  int uid = blockIdx.x * blockDim.x + threadIdx.x;   // 0..65535
  int s   = uid >> 11;
  int nf  = (uid >> 6) & 31;
  int l   = uid & 63;
  int n   = nf * 16 + (l & 15);
  int k0  = s * 32 + (l >> 4) * 8;
  const float* src = w + n * KD + k0;
  float4 a = *reinterpret_cast<const float4*>(src);
  float4 b = *reinterpret_cast<const float4*>(src + 4);
  *reinterpret_cast<u16x8*>(wb + (size_t)uid * 8) = pack8(a, b);
}

// ===== Fused GEMM(32x512, full N) + bias + LN + scale + softmax =============
// R13: 4 INDEPENDENT 4-WAVE BLOCKS PER CU (extends the R6-vs-R7 proven
// independence lever: 2 blocks 121us vs 1 block 133us; now 2 -> 4).
// BM=32, 256 thr / 4 waves (1M x 4N), wave tile 32x128, acc[2][8] (64 AGPR).
// B: rolling half-buffer (pA=frags0-3, pB=frags4-7, 32 VGPR): each half
//    reloaded right after its 8 MFMAs, consumed one full 16-MFMA cluster
//    later (~1240 CU-cyc cover vs ~300-cyc L2 latency).
// A: depth-4 prefetch via 8 x 2 KB LDS bufs (16 KB/block -> 4 blocks/CU),
//    coalesced 128-B row segments, XOR swizzle, no-drain BARRIER (R12).
// Epilogue: no-max softmax, dims adapted to 32 rows x 4-wave reduction.
__global__ __launch_bounds__(256, 4)
void fused_kernel(const float* __restrict__ x,
                  const unsigned short* __restrict__ wb,
                  const float* __restrict__ bias,
                  const float* __restrict__ gamma,
                  const float* __restrict__ beta,
                  const float* __restrict__ scalep,
                  float* __restrict__ out) {
  __shared__ unsigned short As[8][32 * 32];    // 2 KB each, 16 KB total

  const int tid  = threadIdx.x;
  const int lane = tid & 63;
  const int wid  = tid >> 6;        // 0..3 = N quarter: cols wid*128..+127
  const int l15  = lane & 15;
  const int lg   = lane >> 4;       // 0..3

  const long bm  = (long)blockIdx.x * 32;

  f32x4 acc[2][8] = {};

  // ---- A staging: thread t loads x[bm + (t>>3)][ (t&7)*4 .. +3 ] per tile.
  //      8 threads cover one row's 128-B K-slice -> fully coalesced segments.
  //      LDS row = 64 B = 4 chunks of 16 B; chunk c at c ^ ((row>>1)&3).
  const int arow = tid >> 3;        // 0..31
  const int akq  = tid & 7;
  const float* asrc = x + (bm + arow) * KD + akq * 4;
  const int awb = arow * 64 + (((akq >> 1) ^ ((arow >> 1) & 3)) * 16)
                + ((akq & 1) * 8);

  // ---- A fragment read offsets: lane holds A[mi*16+l15][k = lg*8..+7] ----
  const int swa = (lg ^ ((l15 >> 1) & 3)) * 16;
  const int ard0 = (0 * 16 + l15) * 64 + swa;
  const int ard1 = (1 * 16 + l15) * 64 + swa;

  // ---- B fragment base: frag ni of tile t at ((t*32+wid*8+ni)*64+lane)*8 us
  const unsigned short* bbase = wb + ((size_t)(wid * 8) * 64 + lane) * 8;

#define LOADA(t) (*reinterpret_cast<const float4*>(asrc + (t) * 32))

#define LOADB4(t, o, r0, r1, r2, r3) do { \
    const unsigned short* bp_ = bbase + (size_t)(t) * 16384 + (o) * 512; \
    r0 = *reinterpret_cast<const bf16x8*>(bp_ + 0 * 512); \
    r1 = *reinterpret_cast<const bf16x8*>(bp_ + 1 * 512); \
    r2 = *reinterpret_cast<const bf16x8*>(bp_ + 2 * 512); \
    r3 = *reinterpret_cast<const bf16x8*>(bp_ + 3 * 512); } while (0)

#define WRITE_A(q_, bufi) do { \
    union { unsigned short s[4]; unsigned long long v; } c_; \
    c_.s[0] = cvt1(q_.x); c_.s[1] = cvt1(q_.y); \
    c_.s[2] = cvt1(q_.z); c_.s[3] = cvt1(q_.w); \
    *reinterpret_cast<unsigned long long*>((char*)As[bufi] + awb) = c_.v; } while (0)

  // 8 MFMAs: A frags a0,a1 x B frags b0..b3 covering ni = o..o+3
#define HALF(o, b0, b1, b2, b3) do { \
    acc[0][(o)+0] = __builtin_amdgcn_mfma_f32_16x16x32_bf16(a0_, b0, acc[0][(o)+0], 0, 0, 0); \
    acc[0][(o)+1] = __builtin_amdgcn_mfma_f32_16x16x32_bf16(a0_, b1, acc[0][(o)+1], 0, 0, 0); \
    acc[0][(o)+2] = __builtin_amdgcn_mfma_f32_16x16x32_bf16(a0_, b2, acc[0][(o)+2], 0, 0, 0); \
    acc[0][(o)+3] = __builtin_amdgcn_mfma_f32_16x16x32_bf16(a0_, b3, acc[0][(o)+3], 0, 0, 0); \
    acc[1][(o)+0] = __builtin_amdgcn_mfma_f32_16x16x32_bf16(a1_, b0, acc[1][(o)+0], 0, 0, 0); \
    acc[1][(o)+1] = __builtin_amdgcn_mfma_f32_16x16x32_bf16(a1_, b1, acc[1][(o)+1], 0, 0, 0); \
    acc[1][(o)+2] = __builtin_amdgcn_mfma_f32_16x16x32_bf16(a1_, b2, acc[1][(o)+2], 0, 0, 0); \
    acc[1][(o)+3] = __builtin_amdgcn_mfma_f32_16x16x32_bf16(a1_, b3, acc[1][(o)+3], 0, 0, 0); \
    } while (0)

  // one K-tile: 2 ds_read A frags, 16 MFMA, rolling-reload both B halves
#define TILE(bufi, tnext) do { \
    const char* ab_ = (const char*)As[bufi]; \
    bf16x8 a0_ = *reinterpret_cast<const bf16x8*>(ab_ + ard0); \
    bf16x8 a1_ = *reinterpret_cast<const bf16x8*>(ab_ + ard1); \
    HALF(0, pA0, pA1, pA2, pA3); \
    LOADB4(tnext, 0, pA0, pA1, pA2, pA3); \
    HALF(4, pB0, pB1, pB2, pB3); \
    LOADB4(tnext, 4, pB0, pB1, pB2, pB3); \
    } while (0)

  float4 qaE, qaO;
  bf16x8 pA0, pA1, pA2, pA3, pB0, pB1, pB2, pB3;

  // ---- prologue: stage A(0..3) into buf0..3; A(4),A(5) left in flight ----
  qaE = LOADA(0);
  qaO = LOADA(1);
  WRITE_A(qaE, 0);
  WRITE_A(qaO, 1);
  qaE = LOADA(2);
  qaO = LOADA(3);
  WRITE_A(qaE, 2);
  WRITE_A(qaO, 3);
  qaE = LOADA(4);
  qaO = LOADA(5);
  LOADB4(0, 0, pA0, pA1, pA2, pA3);
  LOADB4(0, 4, pB0, pB1, pB2, pB3);
  BARRIER();

  // pair loop: reads buf{t&7,(t+1)&7}; writes buf{(t+4)&7,(t+5)&7} (loads
  // issued one full pair earlier -> landed); issues A(t+6),A(t+7).
  // BARRIER keeps the 4 in-flight A loads alive (no vmcnt drain).
  for (int t = 0; t < NT; t += 2) {
    const int tp6 = (t + 6 < NT) ? t + 6 : NT - 1;   // clamped tail (harmless)
    const int tp7 = (t + 7 < NT) ? t + 7 : NT - 1;
    WRITE_A(qaE, (t + 4) & 7);          // in-flight since top of previous pair
    WRITE_A(qaO, (t + 5) & 7);
    qaE = LOADA(tp6);
    qaO = LOADA(tp7);
    SCHEDB();
    TILE(t & 7, t + 1);
    TILE((t + 1) & 7, (t + 2 < NT) ? t + 2 : NT - 1);
    BARRIER();                          // publish pair's buffers, no vm drain
  }

  // ========== fused epilogue: bias + LN + scale + softmax (no-max) =========
  // |v| <= sqrt(ND) after LN (var=1) -> exp(v) <= 6.5e9, sum < 3.3e12: f32 ok.
  float* redS = (float*)As[0];  // [32][5] partial sums
  float* redQ = redS + 160;     // [32][5] partial sumsq / expsum
  float* rowA = redS + 320;     // [32] mu
  float* rowB = redS + 352;     // [32] rstd, later 1/expsum

  const int col0 = wid * 128 + l15;
  const float sc = scalep[0];
  float bs8[8], gs8[8], bb8[8];
  #pragma unroll
  for (int ni = 0; ni < 8; ++ni) {
    bs8[ni] = bias[col0 + ni * 16];
    gs8[ni] = gamma[col0 + ni * 16] * sc;
    bb8[ni] = beta[col0 + ni * 16] * sc;
  }

  // ---- pass 1: bias add + per-row sum / sumsq ----
  #pragma unroll
  for (int mi = 0; mi < 2; ++mi) {
    #pragma unroll
    for (int j = 0; j < 4; ++j) {
      float s = 0.f, q = 0.f;
      #pragma unroll
      for (int ni = 0; ni < 8; ++ni) {
        float v = acc[mi][ni][j] + bs8[ni];
        acc[mi][ni][j] = v;
        s += v;
        q = fmaf(v, v, q);
      }
      #pragma unroll
      for (int m = 1; m < 16; m <<= 1) {
        s += __shfl_xor(s, m, 64);
        q += __shfl_xor(q, m, 64);
      }
      if (l15 == 0) {
        int r = mi * 16 + lg * 4 + j;
        redS[r * 5 + wid] = s;
        redQ[r * 5 + wid] = q;
      }
    }
  }
  BARRIER();
  if (tid < 32) {
    float s = 0.f, q = 0.f;
    #pragma unroll
    for (int k = 0; k < 4; ++k) { s += redS[tid * 5 + k]; q += redQ[tid * 5 + k]; }
    float mu = s * (1.f / ND);
    rowA[tid] = mu;
    rowB[tid] = rsqrtf(q * (1.f / ND) - mu * mu + EPSV);
  }
  BARRIER();

  // ---- pass 2: normalize + scale + exp; per-row expsum ----
  #pragma unroll
  for (int mi = 0; mi < 2; ++mi) {
    #pragma unroll
    for (int j = 0; j < 4; ++j) {
      int r = mi * 16 + lg * 4 + j;
      float mu = rowA[r], rs = rowB[r];
      float ps = 0.f;
      #pragma unroll
      for (int ni = 0; ni < 8; ++ni) {
        float v = (acc[mi][ni][j] - mu) * rs;
        v = fmaf(v, gs8[ni], bb8[ni]);
        float e = __expf(v);
        acc[mi][ni][j] = e;
        ps += e;
      }
      #pragma unroll
      for (int m = 1; m < 16; m <<= 1) ps += __shfl_xor(ps, m, 64);
      if (l15 == 0) redQ[r * 5 + wid] = ps;
    }
  }
  BARRIER();
  if (tid < 32) {
    float s = 0.f;
    #pragma unroll
    for (int k = 0; k < 4; ++k) s += redQ[tid * 5 + k];
    rowB[tid] = 1.f / s;
  }
  BARRIER();

  // ---- pass 3: store out f32 (non-temporal) ----
  #pragma unroll
  for (int mi = 0; mi < 2; ++mi) {
    #pragma unroll
    for (int j = 0; j < 4; ++j) {
      int r = mi * 16 + lg * 4 + j;
      float rd = rowB[r];
      float* op = out + (bm + r) * ND + col0;
      #pragma unroll
      for (int ni = 0; ni < 8; ++ni)
        __builtin_nontemporal_store(acc[mi][ni][j] * rd, op + ni * 16);
    }
  }
#undef LOADA
#undef LOADB4
#undef WRITE_A
#undef HALF
#undef TILE
}

// trivial last-resort fallback (ws too small; not expected in this harness)
__global__ void fused_fallback(const float* __restrict__ x,
                               const float* __restrict__ wf,
                               const float* __restrict__ bias,
                               const float* __restrict__ gamma,
                               const float* __restrict__ beta,
                               const float* __restrict__ scalep,
                               float* __restrict__ out) {
  long row = blockIdx.x;
  int t = threadIdx.x;
  float s = 0.f;
  const float* xr = x + row * KD;
  const float* wr_ = wf + (size_t)t * KD;
  for (int k = 0; k < KD; ++k) s += xr[k] * wr_[k];
  s += bias[t];
  __shared__ float buf[ND];
  buf[t] = s;
  __syncthreads();
  __shared__ float red[2];
  if (t == 0) {
    float sum = 0.f, sq = 0.f;
    for (int i = 0; i < ND; ++i) { sum += buf[i]; sq += buf[i] * buf[i]; }
    float mu = sum / ND;
    red[0] = mu;
    red[1] = rsqrtf(sq / ND - mu * mu + EPSV);
  }
  __syncthreads();
  float zv = (s - red[0]) * red[1] * gamma[t] * scalep[0] + beta[t] * scalep[0];
  buf[t] = zv;
  __syncthreads();
  __shared__ float red2[2];
  if (t == 0) {
    float mxv = -3.4e38f;
    for (int i = 0; i < ND; ++i) mxv = fmaxf(mxv, buf[i]);
    float den = 0.f;
    for (int i = 0; i < ND; ++i) den += __expf(buf[i] - mxv);
    red2[0] = mxv; red2[1] = 1.f / den;
  }
  __syncthreads();
  out[row * ND + t] = __expf(zv - red2[0]) * red2[1];
}

extern "C" void kernel_launch(void* const* d_in, const int* in_sizes, int n_in,
                              void* d_out, int out_size, void* d_ws, size_t ws_size,
                              hipStream_t stream) {
  const float* x     = (const float*)d_in[0];
  const float* w     = (const float*)d_in[1];
  const float* bias  = (const float*)d_in[2];
  const float* gamma = (const float*)d_in[3];
  const float* beta  = (const float*)d_in[4];
  const float* scale = (const float*)d_in[5];
  float* out = (float*)d_out;

  const int Mrows = in_sizes[0] / KD;                                  // 65536
  const size_t wb_bytes = (size_t)ND * KD * sizeof(unsigned short);    // 1 MB

  if (ws_size >= wb_bytes) {
    unsigned short* wbuf = (unsigned short*)d_ws;
    wconvert_kernel<<<(ND * KD / 8) / 256, 256, 0, stream>>>(w, wbuf);
    fused_kernel<<<Mrows / 32, 256, 0, stream>>>(x, wbuf, bias, gamma, beta,
                                                 scale, out);
  } else {
    fused_fallback<<<Mrows, ND, 0, stream>>>(x, w, bias, gamma, beta, scale, out);
  }
}

// Round 14
// 122.094 us; speedup vs baseline: 1.1006x; 1.1006x over previous
//
#include <hip/hip_runtime.h>
#include <hip/hip_bf16.h>

constexpr int KD = 1024;
constexpr int ND = 512;
constexpr int NT = 32;           // K tiles of 32
constexpr float EPSV = 1e-5f;

using f32x4  = __attribute__((ext_vector_type(4))) float;
using bf16x8 = __attribute__((ext_vector_type(8))) short;
using u16x8  = __attribute__((ext_vector_type(8))) unsigned short;

__device__ __forceinline__ unsigned short f2bf(float f) {
  unsigned int u = __builtin_bit_cast(unsigned int, f);
  return (unsigned short)((u + 0x7fffu + ((u >> 16) & 1u)) >> 16);  // RNE
}

__device__ __forceinline__ u16x8 pack8(float4 a, float4 b) {
  u16x8 v;
  v[0] = f2bf(a.x); v[1] = f2bf(a.y); v[2] = f2bf(a.z); v[3] = f2bf(a.w);
  v[4] = f2bf(b.x); v[5] = f2bf(b.y); v[6] = f2bf(b.z); v[7] = f2bf(b.w);
  return v;
}

__device__ __forceinline__ unsigned short cvt1(float f) {
  __hip_bfloat16 h = __float2bfloat16(f);          // compiler-lowered RNE cvt
  return __builtin_bit_cast(unsigned short, h);
}

#define SCHEDB()  __builtin_amdgcn_sched_barrier(0)

// Barrier WITHOUT vmcnt drain (m201/m218 idiom; R12 verified −3 us, pass):
// lgkmcnt(0) covers every cross-wave LDS hazard; in-flight GLOBAL loads
// target only the issuing wave's registers (gated by compiler vmcnt).
#define BARRIER() do { \
    asm volatile("s_waitcnt lgkmcnt(0)" ::: "memory"); \
    __builtin_amdgcn_sched_barrier(0); \
    __builtin_amdgcn_s_barrier(); \
    __builtin_amdgcn_sched_barrier(0); } while (0)

// wconvert: w [512][1024] f32 -> wb in MFMA-fragment-major bf16 layout.
// unit uid = (s*32 + nf)*64 + lane   (16 B each; s = k-slice 0..31, nf = n-frag)
// holds w[n = nf*16 + (lane&15)][k = s*32 + (lane>>4)*8 + e], e = 0..7.
__global__ void wconvert_kernel(const float* __restrict__ w,
                                unsigned short* __restrict__ wb) {
  int uid = blockIdx.x * blockDim.x + threadIdx.x;   // 0..65535
  int s   = uid >> 11;
  int nf  = (uid >> 6) & 31;
  int l   = uid & 63;
  int n   = nf * 16 + (l & 15);
  int k0  = s * 32 + (l >> 4) * 8;
  const float* src = w + n * KD + k0;
  float4 a = *reinterpret_cast<const float4*>(src);
  float4 b = *reinterpret_cast<const float4*>(src + 4);
  *reinterpret_cast<u16x8*>(wb + (size_t)uid * 8) = pack8(a, b);
}

// ===== Fused GEMM(64x512, full N) + bias + LN + scale + softmax =============
// R14 = R12 (best, 116.2 us) + K-ORDER ROTATION BY BLOCK PARITY: odd blocks
// traverse tiles starting at 16 (mod 32). The two co-resident blocks on a CU
// stop issuing correlated bursts to the same B-tile L2 sets / HBM channels
// in the same barrier window. Accumulation is permutation-invariant.
// Everything else byte-identical to R12: 512 thr / 8 waves (1M x 8N), wave
// tile 64x64, acc[4][4] (64 AGPR), 8 A-LDS buffers (32 KB) depth-4 prefetch,
// no-drain barriers, fragment-major B from L2, no-max softmax epilogue.
// R13 (4x4-wave blocks) regressed 134us — independence lever saturates at 2.
__global__ __launch_bounds__(512, 4)
void fused_kernel(const float* __restrict__ x,
                  const unsigned short* __restrict__ wb,
                  const float* __restrict__ bias,
                  const float* __restrict__ gamma,
                  const float* __restrict__ beta,
                  const float* __restrict__ scalep,
                  float* __restrict__ out) {
  __shared__ unsigned short As[8][64 * 32];    // 4 KB each, 32 KB total

  const int tid  = threadIdx.x;
  const int lane = tid & 63;
  const int wid  = tid >> 6;        // 0..7 = N eighth: cols wid*64..+63
  const int l15  = lane & 15;
  const int lg   = lane >> 4;       // 0..3

  const long bm  = (long)blockIdx.x * 64;
  const int  t0  = (blockIdx.x & 1) << 4;   // phase offset: 0 or 16 tiles

#define TIX(u) ((t0 + (u)) & 31)

  f32x4 acc[4][4] = {};

  // ---- A staging: thread t loads x[bm + (t>>3)][ (t&7)*4 .. +3 ] per tile.
  //      8 threads cover one row's 128-B K-slice -> fully coalesced segments.
  //      LDS row = 64 B = 4 chunks of 16 B; chunk c at c ^ ((row>>1)&3).
  const int arow = tid >> 3;
  const int akq  = tid & 7;
  const float* asrc = x + (bm + arow) * KD + akq * 4;
  const int awb = arow * 64 + (((akq >> 1) ^ ((arow >> 1) & 3)) * 16)
                + ((akq & 1) * 8);

  // ---- A fragment read offsets: lane holds A[mi*16+l15][k = lg*8..+7] ----
  const int swa = (lg ^ ((l15 >> 1) & 3)) * 16;
  int ard[4];
  #pragma unroll
  for (int mi = 0; mi < 4; ++mi) ard[mi] = (mi * 16 + l15) * 64 + swa;

  // ---- B fragment base: frag ni of tile t at ((t*32 + wid*4+ni)*64+lane)*8 us
  const unsigned short* bbase = wb + ((size_t)(wid * 4) * 64 + lane) * 8;

#define LOADA(t) (*reinterpret_cast<const float4*>(asrc + TIX(t) * 32))

#define LOADB(t, r0, r1, r2, r3) do { \
    const unsigned short* bp_ = bbase + (size_t)TIX(t) * 16384; \
    r0 = *reinterpret_cast<const bf16x8*>(bp_ + 0 * 512); \
    r1 = *reinterpret_cast<const bf16x8*>(bp_ + 1 * 512); \
    r2 = *reinterpret_cast<const bf16x8*>(bp_ + 2 * 512); \
    r3 = *reinterpret_cast<const bf16x8*>(bp_ + 3 * 512); } while (0)

#define WRITE_A(q_, bufi) do { \
    union { unsigned short s[4]; unsigned long long v; } c_; \
    c_.s[0] = cvt1(q_.x); c_.s[1] = cvt1(q_.y); \
    c_.s[2] = cvt1(q_.z); c_.s[3] = cvt1(q_.w); \
    *reinterpret_cast<unsigned long long*>((char*)As[bufi] + awb) = c_.v; } while (0)

#define COMPUTE(bufi, B0, B1, B2, B3) do { \
    const char* ab_ = (const char*)As[bufi]; \
    bf16x8 a0_ = *reinterpret_cast<const bf16x8*>(ab_ + ard[0]); \
    bf16x8 a1_ = *reinterpret_cast<const bf16x8*>(ab_ + ard[1]); \
    bf16x8 a2_ = *reinterpret_cast<const bf16x8*>(ab_ + ard[2]); \
    bf16x8 a3_ = *reinterpret_cast<const bf16x8*>(ab_ + ard[3]); \
    acc[0][0] = __builtin_amdgcn_mfma_f32_16x16x32_bf16(a0_, B0, acc[0][0], 0, 0, 0); \
    acc[0][1] = __builtin_amdgcn_mfma_f32_16x16x32_bf16(a0_, B1, acc[0][1], 0, 0, 0); \
    acc[0][2] = __builtin_amdgcn_mfma_f32_16x16x32_bf16(a0_, B2, acc[0][2], 0, 0, 0); \
    acc[0][3] = __builtin_amdgcn_mfma_f32_16x16x32_bf16(a0_, B3, acc[0][3], 0, 0, 0); \
    acc[1][0] = __builtin_amdgcn_mfma_f32_16x16x32_bf16(a1_, B0, acc[1][0], 0, 0, 0); \
    acc[1][1] = __builtin_amdgcn_mfma_f32_16x16x32_bf16(a1_, B1, acc[1][1], 0, 0, 0); \
    acc[1][2] = __builtin_amdgcn_mfma_f32_16x16x32_bf16(a1_, B2, acc[1][2], 0, 0, 0); \
    acc[1][3] = __builtin_amdgcn_mfma_f32_16x16x32_bf16(a1_, B3, acc[1][3], 0, 0, 0); \
    acc[2][0] = __builtin_amdgcn_mfma_f32_16x16x32_bf16(a2_, B0, acc[2][0], 0, 0, 0); \
    acc[2][1] = __builtin_amdgcn_mfma_f32_16x16x32_bf16(a2_, B1, acc[2][1], 0, 0, 0); \
    acc[2][2] = __builtin_amdgcn_mfma_f32_16x16x32_bf16(a2_, B2, acc[2][2], 0, 0, 0); \
    acc[2][3] = __builtin_amdgcn_mfma_f32_16x16x32_bf16(a2_, B3, acc[2][3], 0, 0, 0); \
    acc[3][0] = __builtin_amdgcn_mfma_f32_16x16x32_bf16(a3_, B0, acc[3][0], 0, 0, 0); \
    acc[3][1] = __builtin_amdgcn_mfma_f32_16x16x32_bf16(a3_, B1, acc[3][1], 0, 0, 0); \
    acc[3][2] = __builtin_amdgcn_mfma_f32_16x16x32_bf16(a3_, B2, acc[3][2], 0, 0, 0); \
    acc[3][3] = __builtin_amdgcn_mfma_f32_16x16x32_bf16(a3_, B3, acc[3][3], 0, 0, 0); \
    } while (0)

  float4 qaE, qaO;
  bf16x8 bc0, bc1, bc2, bc3, bn0, bn1, bn2, bn3;

  // ---- prologue: stage tiles u=0..3 into buf0..3; u=4,5 left in flight ----
  qaE = LOADA(0);
  qaO = LOADA(1);
  WRITE_A(qaE, 0);
  WRITE_A(qaO, 1);
  qaE = LOADA(2);
  qaO = LOADA(3);
  WRITE_A(qaE, 2);
  WRITE_A(qaO, 3);
  qaE = LOADA(4);
  qaO = LOADA(5);
  LOADB(0, bc0, bc1, bc2, bc3);
  BARRIER();

  // pair loop over local index u (tile = TIX(u)): reads buf{u&7,(u+1)&7};
  // writes buf{(u+4)&7,(u+5)&7}; issues loads for u+6,u+7. BARRIER keeps
  // the 4 in-flight A loads alive (no vmcnt drain).
  for (int t = 0; t < NT; t += 2) {
    const int tp6 = (t + 6 < NT) ? t + 6 : NT - 1;   // clamped tail (harmless)
    const int tp7 = (t + 7 < NT) ? t + 7 : NT - 1;
    WRITE_A(qaE, (t + 4) & 7);          // in-flight since top of previous pair
    WRITE_A(qaO, (t + 5) & 7);
    qaE = LOADA(tp6);
    qaO = LOADA(tp7);
    LOADB(t + 1, bn0, bn1, bn2, bn3);
    SCHEDB();
    COMPUTE(t & 7, bc0, bc1, bc2, bc3);
    LOADB((t + 2 < NT) ? t + 2 : NT - 1, bc0, bc1, bc2, bc3);
    SCHEDB();
    COMPUTE((t + 1) & 7, bn0, bn1, bn2, bn3);
    BARRIER();                          // publish pair's buffers, no vm drain
  }

  // ========== fused epilogue: bias + LN + scale + softmax (no-max) =========
  // |v| <= sqrt(ND) after LN (var=1) -> exp(v) <= 6.5e9, sum < 3.3e12: f32 ok.
  float* redS = (float*)As[0];  // [64][9] partial sums
  float* redQ = redS + 576;     // [64][9] partial sumsq / expsum
  float* rowA = redS + 1152;    // [64] mu
  float* rowB = redS + 1216;    // [64] rstd, later 1/expsum

  const int col0 = wid * 64 + l15;
  const float sc = scalep[0];
  float bs4[4], gs4[4], bb4[4];
  #pragma unroll
  for (int ni = 0; ni < 4; ++ni) {
    bs4[ni] = bias[col0 + ni * 16];
    gs4[ni] = gamma[col0 + ni * 16] * sc;
    bb4[ni] = beta[col0 + ni * 16] * sc;
  }

  // ---- pass 1: bias add + per-row sum / sumsq ----
  #pragma unroll
  for (int mi = 0; mi < 4; ++mi) {
    #pragma unroll
    for (int j = 0; j < 4; ++j) {
      float s = 0.f, q = 0.f;
      #pragma unroll
      for (int ni = 0; ni < 4; ++ni) {
        float v = acc[mi][ni][j] + bs4[ni];
        acc[mi][ni][j] = v;
        s += v;
        q = fmaf(v, v, q);
      }
      #pragma unroll
      for (int m = 1; m < 16; m <<= 1) {
        s += __shfl_xor(s, m, 64);
        q += __shfl_xor(q, m, 64);
      }
      if (l15 == 0) {
        int r = mi * 16 + lg * 4 + j;
        redS[r * 9 + wid] = s;
        redQ[r * 9 + wid] = q;
      }
    }
  }
  BARRIER();
  if (tid < 64) {
    float s = 0.f, q = 0.f;
    #pragma unroll
    for (int k = 0; k < 8; ++k) { s += redS[tid * 9 + k]; q += redQ[tid * 9 + k]; }
    float mu = s * (1.f / ND);
    rowA[tid] = mu;
    rowB[tid] = rsqrtf(q * (1.f / ND) - mu * mu + EPSV);
  }
  BARRIER();

  // ---- pass 2: normalize + scale + exp; per-row expsum ----
  #pragma unroll
  for (int mi = 0; mi < 4; ++mi) {
    #pragma unroll
    for (int j = 0; j < 4; ++j) {
      int r = mi * 16 + lg * 4 + j;
      float mu = rowA[r], rs = rowB[r];
      float ps = 0.f;
      #pragma unroll
      for (int ni = 0; ni < 4; ++ni) {
        float v = (acc[mi][ni][j] - mu) * rs;
        v = fmaf(v, gs4[ni], bb4[ni]);
        float e = __expf(v);
        acc[mi][ni][j] = e;
        ps += e;
      }
      #pragma unroll
      for (int m = 1; m < 16; m <<= 1) ps += __shfl_xor(ps, m, 64);
      if (l15 == 0) redQ[r * 9 + wid] = ps;
    }
  }
  BARRIER();
  if (tid < 64) {
    float s = 0.f;
    #pragma unroll
    for (int k = 0; k < 8; ++k) s += redQ[tid * 9 + k];
    rowB[tid] = 1.f / s;
  }
  BARRIER();

  // ---- pass 3: store out f32 (non-temporal) ----
  #pragma unroll
  for (int mi = 0; mi < 4; ++mi) {
    #pragma unroll
    for (int j = 0; j < 4; ++j) {
      int r = mi * 16 + lg * 4 + j;
      float rd = rowB[r];
      float* op = out + (bm + r) * ND + col0;
      #pragma unroll
      for (int ni = 0; ni < 4; ++ni)
        __builtin_nontemporal_store(acc[mi][ni][j] * rd, op + ni * 16);
    }
  }
#undef LOADA
#undef LOADB
#undef WRITE_A
#undef COMPUTE
#undef TIX
}

// trivial last-resort fallback (ws too small; not expected in this harness)
__global__ void fused_fallback(const float* __restrict__ x,
                               const float* __restrict__ wf,
                               const float* __restrict__ bias,
                               const float* __restrict__ gamma,
                               const float* __restrict__ beta,
                               const float* __restrict__ scalep,
                               float* __restrict__ out) {
  long row = blockIdx.x;
  int t = threadIdx.x;
  float s = 0.f;
  const float* xr = x + row * KD;
  const float* wr_ = wf + (size_t)t * KD;
  for (int k = 0; k < KD; ++k) s += xr[k] * wr_[k];
  s += bias[t];
  __shared__ float buf[ND];
  buf[t] = s;
  __syncthreads();
  __shared__ float red[2];
  if (t == 0) {
    float sum = 0.f, sq = 0.f;
    for (int i = 0; i < ND; ++i) { sum += buf[i]; sq += buf[i] * buf[i]; }
    float mu = sum / ND;
    red[0] = mu;
    red[1] = rsqrtf(sq / ND - mu * mu + EPSV);
  }
  __syncthreads();
  float zv = (s - red[0]) * red[1] * gamma[t] * scalep[0] + beta[t] * scalep[0];
  buf[t] = zv;
  __syncthreads();
  __shared__ float red2[2];
  if (t == 0) {
    float mxv = -3.4e38f;
    for (int i = 0; i < ND; ++i) mxv = fmaxf(mxv, buf[i]);
    float den = 0.f;
    for (int i = 0; i < ND; ++i) den += __expf(buf[i] - mxv);
    red2[0] = mxv; red2[1] = 1.f / den;
  }
  __syncthreads();
  out[row * ND + t] = __expf(zv - red2[0]) * red2[1];
}

extern "C" void kernel_launch(void* const* d_in, const int* in_sizes, int n_in,
                              void* d_out, int out_size, void* d_ws, size_t ws_size,
                              hipStream_t stream) {
  const float* x     = (const float*)d_in[0];
  const float* w     = (const float*)d_in[1];
  const float* bias  = (const float*)d_in[2];
  const float* gamma = (const float*)d_in[3];
  const float* beta  = (const float*)d_in[4];
  const float* scale = (const float*)d_in[5];
  float* out = (float*)d_out;

  const int Mrows = in_sizes[0] / KD;                                  // 65536
  const size_t wb_bytes = (size_t)ND * KD * sizeof(unsigned short);    // 1 MB

  if (ws_size >= wb_bytes) {
    unsigned short* wbuf = (unsigned short*)d_ws;
    wconvert_kernel<<<(ND * KD / 8) / 256, 256, 0, stream>>>(w, wbuf);
    fused_kernel<<<Mrows / 64, 512, 0, stream>>>(x, wbuf, bias, gamma, beta,
                                                 scale, out);
  } else {
    fused_fallback<<<Mrows, ND, 0, stream>>>(x, w, bias, gamma, beta, scale, out);
  }
}

// Round 15
// 115.948 us; speedup vs baseline: 1.1590x; 1.0530x over previous
//
#include <hip/hip_runtime.h>
#include <hip/hip_bf16.h>

constexpr int KD = 1024;
constexpr int ND = 512;
constexpr int NT = 32;           // K tiles of 32
constexpr float EPSV = 1e-5f;

using f32x4  = __attribute__((ext_vector_type(4))) float;
using bf16x8 = __attribute__((ext_vector_type(8))) short;
using u16x8  = __attribute__((ext_vector_type(8))) unsigned short;

__device__ __forceinline__ unsigned short f2bf(float f) {
  unsigned int u = __builtin_bit_cast(unsigned int, f);
  return (unsigned short)((u + 0x7fffu + ((u >> 16) & 1u)) >> 16);  // RNE
}

__device__ __forceinline__ u16x8 pack8(float4 a, float4 b) {
  u16x8 v;
  v[0] = f2bf(a.x); v[1] = f2bf(a.y); v[2] = f2bf(a.z); v[3] = f2bf(a.w);
  v[4] = f2bf(b.x); v[5] = f2bf(b.y); v[6] = f2bf(b.z); v[7] = f2bf(b.w);
  return v;
}

__device__ __forceinline__ unsigned short cvt1(float f) {
  __hip_bfloat16 h = __float2bfloat16(f);          // compiler-lowered RNE cvt
  return __builtin_bit_cast(unsigned short, h);
}

#define SCHEDB()  __builtin_amdgcn_sched_barrier(0)

// Barrier WITHOUT vmcnt drain (m201/m218 idiom; R12 verified −3 us, pass):
// lgkmcnt(0) covers every cross-wave LDS hazard; in-flight GLOBAL loads
// target only the issuing wave's registers (gated by compiler vmcnt).
#define BARRIER() do { \
    asm volatile("s_waitcnt lgkmcnt(0)" ::: "memory"); \
    __builtin_amdgcn_sched_barrier(0); \
    __builtin_amdgcn_s_barrier(); \
    __builtin_amdgcn_sched_barrier(0); } while (0)

// wconvert: w [512][1024] f32 -> wb in MFMA-fragment-major bf16 layout.
// unit uid = (s*32 + nf)*64 + lane   (16 B each; s = k-slice 0..31, nf = n-frag)
// holds w[n = nf*16 + (lane&15)][k = s*32 + (lane>>4)*8 + e], e = 0..7.
__global__ void wconvert_kernel(const float* __restrict__ w,
                                unsigned short* __restrict__ wb) {
  int uid = blockIdx.x * blockDim.x + threadIdx.x;   // 0..65535
  int s   = uid >> 11;
  int nf  = (uid >> 6) & 31;
  int l   = uid & 63;
  int n   = nf * 16 + (l & 15);
  int k0  = s * 32 + (l >> 4) * 8;
  const float* src = w + n * KD + k0;
  float4 a = *reinterpret_cast<const float4*>(src);
  float4 b = *reinterpret_cast<const float4*>(src + 4);
  *reinterpret_cast<u16x8*>(wb + (size_t)uid * 8) = pack8(a, b);
}

// ===== Fused GEMM(64x512, full N) + bias + LN + scale + softmax =============
// R15 = R12 RESTORED (session best, 116.2 us). R14's K-rotation regressed
// (−6 us): co-resident blocks' correlated B traversal is an L2-reuse WIN,
// not a contention cost. Ledger of this structure's proven components:
//  - fused single kernel, full-N block rows (R1)
//  - BM=64, 8 waves, wave tile 64x64, acc[4][4]; B fragment-major from L2
//    straight to regs, 1-tile reg-dbuf (R4)
//  - block-shared coalesced A staging, 128-B segments, XOR swizzle (R4/R6)
//  - A-prefetch depth 4 via 8 LDS buffers, 2 blocks/CU (R10)
//  - barriers WITHOUT vmcnt drain (R12)
//  - no-max softmax epilogue: LN bounds |v| <= sqrt(512) (R6)
// Register file is fully allocated (64 VGPR + 64 AGPR x 4 waves/SIMD);
// no pipe >19%; conflicts/over-fetch/spill all zero.
__global__ __launch_bounds__(512, 4)
void fused_kernel(const float* __restrict__ x,
                  const unsigned short* __restrict__ wb,
                  const float* __restrict__ bias,
                  const float* __restrict__ gamma,
                  const float* __restrict__ beta,
                  const float* __restrict__ scalep,
                  float* __restrict__ out) {
  __shared__ unsigned short As[8][64 * 32];    // 4 KB each, 32 KB total

  const int tid  = threadIdx.x;
  const int lane = tid & 63;
  const int wid  = tid >> 6;        // 0..7 = N eighth: cols wid*64..+63
  const int l15  = lane & 15;
  const int lg   = lane >> 4;       // 0..3

  const long bm  = (long)blockIdx.x * 64;

  f32x4 acc[4][4] = {};

  // ---- A staging: thread t loads x[bm + (t>>3)][ (t&7)*4 .. +3 ] per tile.
  //      8 threads cover one row's 128-B K-slice -> fully coalesced segments.
  //      LDS row = 64 B = 4 chunks of 16 B; chunk c at c ^ ((row>>1)&3).
  const int arow = tid >> 3;
  const int akq  = tid & 7;
  const float* asrc = x + (bm + arow) * KD + akq * 4;
  const int awb = arow * 64 + (((akq >> 1) ^ ((arow >> 1) & 3)) * 16)
                + ((akq & 1) * 8);

  // ---- A fragment read offsets: lane holds A[mi*16+l15][k = lg*8..+7] ----
  const int swa = (lg ^ ((l15 >> 1) & 3)) * 16;
  int ard[4];
  #pragma unroll
  for (int mi = 0; mi < 4; ++mi) ard[mi] = (mi * 16 + l15) * 64 + swa;

  // ---- B fragment base: frag ni of tile t at ((t*32 + wid*4+ni)*64+lane)*8 us
  const unsigned short* bbase = wb + ((size_t)(wid * 4) * 64 + lane) * 8;

#define LOADA(t) (*reinterpret_cast<const float4*>(asrc + (t) * 32))

#define LOADB(t, r0, r1, r2, r3) do { \
    const unsigned short* bp_ = bbase + (size_t)(t) * 16384; \
    r0 = *reinterpret_cast<const bf16x8*>(bp_ + 0 * 512); \
    r1 = *reinterpret_cast<const bf16x8*>(bp_ + 1 * 512); \
    r2 = *reinterpret_cast<const bf16x8*>(bp_ + 2 * 512); \
    r3 = *reinterpret_cast<const bf16x8*>(bp_ + 3 * 512); } while (0)

#define WRITE_A(q_, bufi) do { \
    union { unsigned short s[4]; unsigned long long v; } c_; \
    c_.s[0] = cvt1(q_.x); c_.s[1] = cvt1(q_.y); \
    c_.s[2] = cvt1(q_.z); c_.s[3] = cvt1(q_.w); \
    *reinterpret_cast<unsigned long long*>((char*)As[bufi] + awb) = c_.v; } while (0)

#define COMPUTE(bufi, B0, B1, B2, B3) do { \
    const char* ab_ = (const char*)As[bufi]; \
    bf16x8 a0_ = *reinterpret_cast<const bf16x8*>(ab_ + ard[0]); \
    bf16x8 a1_ = *reinterpret_cast<const bf16x8*>(ab_ + ard[1]); \
    bf16x8 a2_ = *reinterpret_cast<const bf16x8*>(ab_ + ard[2]); \
    bf16x8 a3_ = *reinterpret_cast<const bf16x8*>(ab_ + ard[3]); \
    acc[0][0] = __builtin_amdgcn_mfma_f32_16x16x32_bf16(a0_, B0, acc[0][0], 0, 0, 0); \
    acc[0][1] = __builtin_amdgcn_mfma_f32_16x16x32_bf16(a0_, B1, acc[0][1], 0, 0, 0); \
    acc[0][2] = __builtin_amdgcn_mfma_f32_16x16x32_bf16(a0_, B2, acc[0][2], 0, 0, 0); \
    acc[0][3] = __builtin_amdgcn_mfma_f32_16x16x32_bf16(a0_, B3, acc[0][3], 0, 0, 0); \
    acc[1][0] = __builtin_amdgcn_mfma_f32_16x16x32_bf16(a1_, B0, acc[1][0], 0, 0, 0); \
    acc[1][1] = __builtin_amdgcn_mfma_f32_16x16x32_bf16(a1_, B1, acc[1][1], 0, 0, 0); \
    acc[1][2] = __builtin_amdgcn_mfma_f32_16x16x32_bf16(a1_, B2, acc[1][2], 0, 0, 0); \
    acc[1][3] = __builtin_amdgcn_mfma_f32_16x16x32_bf16(a1_, B3, acc[1][3], 0, 0, 0); \
    acc[2][0] = __builtin_amdgcn_mfma_f32_16x16x32_bf16(a2_, B0, acc[2][0], 0, 0, 0); \
    acc[2][1] = __builtin_amdgcn_mfma_f32_16x16x32_bf16(a2_, B1, acc[2][1], 0, 0, 0); \
    acc[2][2] = __builtin_amdgcn_mfma_f32_16x16x32_bf16(a2_, B2, acc[2][2], 0, 0, 0); \
    acc[2][3] = __builtin_amdgcn_mfma_f32_16x16x32_bf16(a2_, B3, acc[2][3], 0, 0, 0); \
    acc[3][0] = __builtin_amdgcn_mfma_f32_16x16x32_bf16(a3_, B0, acc[3][0], 0, 0, 0); \
    acc[3][1] = __builtin_amdgcn_mfma_f32_16x16x32_bf16(a3_, B1, acc[3][1], 0, 0, 0); \
    acc[3][2] = __builtin_amdgcn_mfma_f32_16x16x32_bf16(a3_, B2, acc[3][2], 0, 0, 0); \
    acc[3][3] = __builtin_amdgcn_mfma_f32_16x16x32_bf16(a3_, B3, acc[3][3], 0, 0, 0); \
    } while (0)

  float4 qaE, qaO;
  bf16x8 bc0, bc1, bc2, bc3, bn0, bn1, bn2, bn3;

  // ---- prologue: stage A(0..3) into buf0..3; A(4),A(5) left in flight ----
  qaE = LOADA(0);
  qaO = LOADA(1);
  WRITE_A(qaE, 0);
  WRITE_A(qaO, 1);
  qaE = LOADA(2);
  qaO = LOADA(3);
  WRITE_A(qaE, 2);
  WRITE_A(qaO, 3);
  qaE = LOADA(4);
  qaO = LOADA(5);
  LOADB(0, bc0, bc1, bc2, bc3);
  BARRIER();

  // pair loop: reads buf{t&7,(t+1)&7}; writes buf{(t+4)&7,(t+5)&7} (loads
  // issued one full pair earlier -> landed); issues A(t+6),A(t+7).
  // The BARRIER keeps those 4 A-loads in flight (no vmcnt drain).
  for (int t = 0; t < NT; t += 2) {
    const int tp6 = (t + 6 < NT) ? t + 6 : NT - 1;   // clamped tail (harmless)
    const int tp7 = (t + 7 < NT) ? t + 7 : NT - 1;
    WRITE_A(qaE, (t + 4) & 7);          // in-flight since top of previous pair
    WRITE_A(qaO, (t + 5) & 7);
    qaE = LOADA(tp6);
    qaO = LOADA(tp7);
    LOADB(t + 1, bn0, bn1, bn2, bn3);
    SCHEDB();
    COMPUTE(t & 7, bc0, bc1, bc2, bc3);
    LOADB((t + 2 < NT) ? t + 2 : NT - 1, bc0, bc1, bc2, bc3);
    SCHEDB();
    COMPUTE((t + 1) & 7, bn0, bn1, bn2, bn3);
    BARRIER();                          // publish pair's buffers, no vm drain
  }

  // ========== fused epilogue: bias + LN + scale + softmax (no-max) =========
  // |v| <= sqrt(ND) after LN (var=1) -> exp(v) <= 6.5e9, sum < 3.3e12: f32 ok.
  float* redS = (float*)As[0];  // [64][9] partial sums
  float* redQ = redS + 576;     // [64][9] partial sumsq / expsum
  float* rowA = redS + 1152;    // [64] mu
  float* rowB = redS + 1216;    // [64] rstd, later 1/expsum

  const int col0 = wid * 64 + l15;
  const float sc = scalep[0];
  float bs4[4], gs4[4], bb4[4];
  #pragma unroll
  for (int ni = 0; ni < 4; ++ni) {
    bs4[ni] = bias[col0 + ni * 16];
    gs4[ni] = gamma[col0 + ni * 16] * sc;
    bb4[ni] = beta[col0 + ni * 16] * sc;
  }

  // ---- pass 1: bias add + per-row sum / sumsq ----
  #pragma unroll
  for (int mi = 0; mi < 4; ++mi) {
    #pragma unroll
    for (int j = 0; j < 4; ++j) {
      float s = 0.f, q = 0.f;
      #pragma unroll
      for (int ni = 0; ni < 4; ++ni) {
        float v = acc[mi][ni][j] + bs4[ni];
        acc[mi][ni][j] = v;
        s += v;
        q = fmaf(v, v, q);
      }
      #pragma unroll
      for (int m = 1; m < 16; m <<= 1) {
        s += __shfl_xor(s, m, 64);
        q += __shfl_xor(q, m, 64);
      }
      if (l15 == 0) {
        int r = mi * 16 + lg * 4 + j;
        redS[r * 9 + wid] = s;
        redQ[r * 9 + wid] = q;
      }
    }
  }
  BARRIER();
  if (tid < 64) {
    float s = 0.f, q = 0.f;
    #pragma unroll
    for (int k = 0; k < 8; ++k) { s += redS[tid * 9 + k]; q += redQ[tid * 9 + k]; }
    float mu = s * (1.f / ND);
    rowA[tid] = mu;
    rowB[tid] = rsqrtf(q * (1.f / ND) - mu * mu + EPSV);
  }
  BARRIER();

  // ---- pass 2: normalize + scale + exp; per-row expsum ----
  #pragma unroll
  for (int mi = 0; mi < 4; ++mi) {
    #pragma unroll
    for (int j = 0; j < 4; ++j) {
      int r = mi * 16 + lg * 4 + j;
      float mu = rowA[r], rs = rowB[r];
      float ps = 0.f;
      #pragma unroll
      for (int ni = 0; ni < 4; ++ni) {
        float v = (acc[mi][ni][j] - mu) * rs;
        v = fmaf(v, gs4[ni], bb4[ni]);
        float e = __expf(v);
        acc[mi][ni][j] = e;
        ps += e;
      }
      #pragma unroll
      for (int m = 1; m < 16; m <<= 1) ps += __shfl_xor(ps, m, 64);
      if (l15 == 0) redQ[r * 9 + wid] = ps;
    }
  }
  BARRIER();
  if (tid < 64) {
    float s = 0.f;
    #pragma unroll
    for (int k = 0; k < 8; ++k) s += redQ[tid * 9 + k];
    rowB[tid] = 1.f / s;
  }
  BARRIER();

  // ---- pass 3: store out f32 (non-temporal) ----
  #pragma unroll
  for (int mi = 0; mi < 4; ++mi) {
    #pragma unroll
    for (int j = 0; j < 4; ++j) {
      int r = mi * 16 + lg * 4 + j;
      float rd = rowB[r];
      float* op = out + (bm + r) * ND + col0;
      #pragma unroll
      for (int ni = 0; ni < 4; ++ni)
        __builtin_nontemporal_store(acc[mi][ni][j] * rd, op + ni * 16);
    }
  }
#undef LOADA
#undef LOADB
#undef WRITE_A
#undef COMPUTE
}

// trivial last-resort fallback (ws too small; not expected in this harness)
__global__ void fused_fallback(const float* __restrict__ x,
                               const float* __restrict__ wf,
                               const float* __restrict__ bias,
                               const float* __restrict__ gamma,
                               const float* __restrict__ beta,
                               const float* __restrict__ scalep,
                               float* __restrict__ out) {
  long row = blockIdx.x;
  int t = threadIdx.x;
  float s = 0.f;
  const float* xr = x + row * KD;
  const float* wr_ = wf + (size_t)t * KD;
  for (int k = 0; k < KD; ++k) s += xr[k] * wr_[k];
  s += bias[t];
  __shared__ float buf[ND];
  buf[t] = s;
  __syncthreads();
  __shared__ float red[2];
  if (t == 0) {
    float sum = 0.f, sq = 0.f;
    for (int i = 0; i < ND; ++i) { sum += buf[i]; sq += buf[i] * buf[i]; }
    float mu = sum / ND;
    red[0] = mu;
    red[1] = rsqrtf(sq / ND - mu * mu + EPSV);
  }
  __syncthreads();
  float zv = (s - red[0]) * red[1] * gamma[t] * scalep[0] + beta[t] * scalep[0];
  buf[t] = zv;
  __syncthreads();
  __shared__ float red2[2];
  if (t == 0) {
    float mxv = -3.4e38f;
    for (int i = 0; i < ND; ++i) mxv = fmaxf(mxv, buf[i]);
    float den = 0.f;
    for (int i = 0; i < ND; ++i) den += __expf(buf[i] - mxv);
    red2[0] = mxv; red2[1] = 1.f / den;
  }
  __syncthreads();
  out[row * ND + t] = __expf(zv - red2[0]) * red2[1];
}

extern "C" void kernel_launch(void* const* d_in, const int* in_sizes, int n_in,
                              void* d_out, int out_size, void* d_ws, size_t ws_size,
                              hipStream_t stream) {
  const float* x     = (const float*)d_in[0];
  const float* w     = (const float*)d_in[1];
  const float* bias  = (const float*)d_in[2];
  const float* gamma = (const float*)d_in[3];
  const float* beta  = (const float*)d_in[4];
  const float* scale = (const float*)d_in[5];
  float* out = (float*)d_out;

  const int Mrows = in_sizes[0] / KD;                                  // 65536
  const size_t wb_bytes = (size_t)ND * KD * sizeof(unsigned short);    // 1 MB

  if (ws_size >= wb_bytes) {
    unsigned short* wbuf = (unsigned short*)d_ws;
    wconvert_kernel<<<(ND * KD / 8) / 256, 256, 0, stream>>>(w, wbuf);
    fused_kernel<<<Mrows / 64, 512, 0, stream>>>(x, wbuf, bias, gamma, beta,
                                                 scale, out);
  } else {
    fused_fallback<<<Mrows, ND, 0, stream>>>(x, w, bias, gamma, beta, scale, out);
  }
}